// Round 13
// baseline (9247.396 us; speedup 1.0000x reference)
//
#include <hip/hip_runtime.h>
#include <hip/hip_bf16.h>

// LSTM: T=8192, IN=3000, H=100 (4H=400), torch gate order i,f,g,o.
// Phase 1: xg[T][400] = input @ w_ih^T + (b_ih+b_hh), PERMUTED cols (4u+g).
// Phase 2: single-workgroup MFMA scan (R8/R11 structure, best at ~1390
//          cyc/step). R9/R10/R11 scheduling fixes were null; R12 dot2 engine
//          regressed (1700 cyc/step). Cost model is off by ~500 cyc/step.
// ROUND-13 = DIAGNOSTIC ABLATION (guide common-mistake #8, m164/m165):
//   template<int MODE> variants dispatched serially; rocprof per-dispatch
//   dur_us decomposes the step: 0=full(real out), 1=noMFMA, 2=no ds_read,
//   3=no transcendentals, 4=no barrier. Ablations run T/4 steps and write
//   into the xg tail (rewritten by the GEMM each replay; real scan already
//   consumed it) so d_out stays correct.

#define GBM 128
#define GBN 128
#define GBK 16

typedef _Float16 h2_t  __attribute__((ext_vector_type(2)));
typedef _Float16 f16x8 __attribute__((ext_vector_type(8)));
typedef float    f32x4 __attribute__((ext_vector_type(4)));

__global__ __launch_bounds__(256) void gates_gemm(
    const float* __restrict__ A,    // [T][IN]
    const float* __restrict__ W,    // [FH][IN]
    const float* __restrict__ bih,  // [FH]
    const float* __restrict__ bhh,  // [FH]
    float* __restrict__ XG,         // [T][FH]  (permuted columns)
    int T, int IN, int FH)
{
    __shared__ __align__(16) float As[GBK][GBM];
    __shared__ __align__(16) float Bs[GBK][GBN];
    const int bm = blockIdx.x * GBM;
    const int bn = blockIdx.y * GBN;
    const int tid = (int)threadIdx.x;
    const int tx = tid & 15, ty = tid >> 4;
    const int H = FH >> 2;   // 100

    float acc[8][8];
    #pragma unroll
    for (int i = 0; i < 8; ++i)
        #pragma unroll
        for (int j = 0; j < 8; ++j) acc[i][j] = 0.f;

    for (int k0 = 0; k0 < IN; k0 += GBK) {
        __syncthreads();
        #pragma unroll
        for (int q = 0; q < 2; ++q) {
            int idx = tid + q * 256;
            int row = idx >> 2;
            int kq  = (idx & 3) << 2;
            int gk  = k0 + kq;
            float4 av = make_float4(0.f, 0.f, 0.f, 0.f);
            float4 bv = make_float4(0.f, 0.f, 0.f, 0.f);
            if (gk < IN) {
                av = *(const float4*)&A[(size_t)(bm + row) * IN + gk];
                if (bn + row < FH)
                    bv = *(const float4*)&W[(size_t)(bn + row) * IN + gk];
            }
            As[kq + 0][row] = av.x; As[kq + 1][row] = av.y;
            As[kq + 2][row] = av.z; As[kq + 3][row] = av.w;
            Bs[kq + 0][row] = bv.x; Bs[kq + 1][row] = bv.y;
            Bs[kq + 2][row] = bv.z; Bs[kq + 3][row] = bv.w;
        }
        __syncthreads();
        #pragma unroll
        for (int kk = 0; kk < GBK; ++kk) {
            float4 a0 = *(const float4*)&As[kk][ty * 4];
            float4 a1 = *(const float4*)&As[kk][64 + ty * 4];
            float4 b0 = *(const float4*)&Bs[kk][tx * 4];
            float4 b1 = *(const float4*)&Bs[kk][64 + tx * 4];
            float am[8] = {a0.x, a0.y, a0.z, a0.w, a1.x, a1.y, a1.z, a1.w};
            float bn_[8] = {b0.x, b0.y, b0.z, b0.w, b1.x, b1.y, b1.z, b1.w};
            #pragma unroll
            for (int i = 0; i < 8; ++i)
                #pragma unroll
                for (int j = 0; j < 8; ++j)
                    acc[i][j] = fmaf(am[i], bn_[j], acc[i][j]);
        }
    }

    #pragma unroll
    for (int i = 0; i < 8; ++i) {
        int r = bm + ((i < 4) ? (ty * 4 + i) : (64 + ty * 4 + (i - 4)));
        #pragma unroll
        for (int j = 0; j < 8; ++j) {
            int cidx = bn + ((j < 4) ? (tx * 4 + j) : (64 + tx * 4 + (j - 4)));
            if (cidx < FH) {
                int pc = 4 * (cidx % H) + cidx / H;   // unit-major permutation
                XG[(size_t)r * FH + pc] = acc[i][j] + bih[cidx] + bhh[cidx];
            }
        }
    }
}

__device__ __forceinline__ float sigmoid_fast(float x) {
    return 1.f / (1.f + __expf(-x));
}
__device__ __forceinline__ float tanh_fast(float x) {
    return 1.f - 2.f / (__expf(2.f * x) + 1.f);
}

// pack W[k], W[k+1] (f32) into one dword of two f16 (zero past K=100)
__device__ __forceinline__ float pack_pair(const float* rp, int k) {
    float a = 0.f, b = 0.f;
    if (k < 100) { a = rp[k]; b = rp[k + 1]; }
    h2_t p = {(_Float16)a, (_Float16)b};
    return __builtin_bit_cast(float, p);
}

#define ACLOB \
    "a0","a1","a2","a3","a4","a5","a6","a7","a8","a9","a10","a11","a12","a13",\
    "a14","a15","a16","a17","a18","a19","a20","a21","a22","a23","a24","a25",\
    "a26","a27","a28","a29","a30","a31","a32","a33","a34","a35","a36","a37",\
    "a38","a39","a40","a41","a42","a43","a44","a45","a46","a47","a48","a49",\
    "a50","a51","a52","a53","a54","a55","a56","a57","a58","a59","a60","a61",\
    "a62","a63","a64","a65","a66","a67","a68","a69","a70","a71","a72","a73",\
    "a74","a75","a76","a77","a78","a79","a80","a81","a82","a83","a84","a85",\
    "a86","a87","a88","a89","a90","a91","a92","a93","a94","a95","a96","a97",\
    "a98","a99","a100","a101","a102","a103","a104","a105","a106","a107",\
    "a108","a109","a110","a111"

#define WRW(N, V) \
    asm volatile("v_accvgpr_write_b32 a" #N ", %0" :: "v"(V) : "a" #N)

#define LF(m, ks, N0, N1, N2, N3) { \
    const int kb_ = 32 * (ks) + 8 * q; \
    WRW(N0, pack_pair(rowp[m], kb_ + 0)); \
    WRW(N1, pack_pair(rowp[m], kb_ + 2)); \
    WRW(N2, pack_pair(rowp[m], kb_ + 4)); \
    WRW(N3, pack_pair(rowp[m], kb_ + 6)); }

#define MF(ACC, AR, B) \
    asm volatile("v_mfma_f32_16x16x32_f16 %0, " AR ", %1, %0" \
                 : "+v"(ACC) : "v"(B) : ACLOB)

// raw barrier: orders LDS (lgkmcnt) but leaves global loads in flight
#define BAR() asm volatile("s_waitcnt lgkmcnt(0)\n\ts_barrier" ::: "memory")

template <int MODE>   // 0=full 1=noMFMA 2=noDSread 3=noELT 4=noBARRIER
__global__ __launch_bounds__(256, 1) void lstm_ablate(
    const float* __restrict__ XGp,   // [T][400] permuted (4u+g)
    const float* __restrict__ Whh,   // [400][100] original layout
    const float* __restrict__ wlin,  // [100]
    const float* __restrict__ blin,  // [1]
    float* __restrict__ outp, int T)
{
    __shared__ __align__(16) _Float16 hbuf[2][128];
    __shared__ float hfin[100];
    const int tid = (int)threadIdx.x;
    const int w   = tid >> 6;
    const int l   = tid & 63;
    const int q   = l >> 4;
    const int col = l & 15;
    const int NT  = (w == 0) ? 7 : 6;
    const int tb  = (w == 0) ? 0 : 7 + 6 * (w - 1);

    const float* rowp[7];
    #pragma unroll
    for (int m = 0; m < 7; ++m) {
        int mg = tb + m; if (mg > 24) mg = 24;
        int R  = 16 * mg + col;
        rowp[m] = Whh + (size_t)((R >> 2) + 100 * (R & 3)) * 100;
    }

    LF(0,0,  0,  1,  2,  3)  LF(0,1,  4,  5,  6,  7)
    LF(0,2,  8,  9, 10, 11)  LF(0,3, 12, 13, 14, 15)
    LF(1,0, 16, 17, 18, 19)  LF(1,1, 20, 21, 22, 23)
    LF(1,2, 24, 25, 26, 27)  LF(1,3, 28, 29, 30, 31)
    LF(2,0, 32, 33, 34, 35)  LF(2,1, 36, 37, 38, 39)
    LF(2,2, 40, 41, 42, 43)  LF(2,3, 44, 45, 46, 47)
    LF(3,0, 48, 49, 50, 51)  LF(3,1, 52, 53, 54, 55)
    LF(3,2, 56, 57, 58, 59)  LF(3,3, 60, 61, 62, 63)
    LF(4,0, 64, 65, 66, 67)  LF(4,1, 68, 69, 70, 71)
    LF(4,2, 72, 73, 74, 75)  LF(4,3, 76, 77, 78, 79)
    LF(5,0, 80, 81, 82, 83)  LF(5,1, 84, 85, 86, 87)
    LF(5,2, 88, 89, 90, 91)  LF(5,3, 92, 93, 94, 95)
    LF(6,0, 96, 97, 98, 99)  LF(6,1,100,101,102,103)
    LF(6,2,104,105,106,107)  LF(6,3,108,109,110,111)

    if (tid < 128) {
        hbuf[0][tid] = (_Float16)0.f;
        hbuf[1][tid] = (_Float16)0.f;
    }

    const bool act = (col < NT);
    const int  u   = act ? (4 * (tb + col) + q) : 0;

    float c = 0.f, hlast = 0.f;
    int cur = 0;

#define XROW(i) (*(const f32x4*)(XGp + (size_t)((i) < T ? (i) : (T - 1)) * 400 + 4 * u))
    f32x4 xa = XROW(0), xb = XROW(1), xc = XROW(2), xd = XROW(3);
    BAR();

#define SUBSTEP(XP, TNEXT) { \
    f32x4 xnew_ = XROW(TNEXT); \
    f16x8 b0, b1, b2, b3; \
    if constexpr (MODE != 2) { \
        const _Float16* hb = hbuf[cur]; \
        b0 = *(const f16x8*)(hb +       8 * q); \
        b1 = *(const f16x8*)(hb +  32 + 8 * q); \
        b2 = *(const f16x8*)(hb +  64 + 8 * q); \
        b3 = *(const f16x8*)(hb +  96 + 8 * q); \
    } else { \
        b0 = __builtin_bit_cast(f16x8, XP); b1 = b0; b2 = b0; b3 = b0; \
        asm("" : "+v"(b0), "+v"(b1), "+v"(b2), "+v"(b3)); \
    } \
    f32x4 acc0 = XP, acc1 = XP, acc2 = XP, acc3 = XP; \
    f32x4 acc4 = XP, acc5 = XP, acc6 = XP; \
    int colg; \
    if constexpr (MODE != 1) { \
        asm volatile("s_nop 1" ::: ); \
        MF(acc0, "a[0:3]",   b0); MF(acc1, "a[16:19]", b0); \
        MF(acc2, "a[32:35]", b0); MF(acc3, "a[48:51]", b0); \
        MF(acc4, "a[64:67]", b0); MF(acc5, "a[80:83]", b0); \
        MF(acc6, "a[96:99]", b0); \
        MF(acc0, "a[4:7]",   b1); MF(acc1, "a[20:23]", b1); \
        MF(acc2, "a[36:39]", b1); MF(acc3, "a[52:55]", b1); \
        MF(acc4, "a[68:71]", b1); MF(acc5, "a[84:87]", b1); \
        MF(acc6, "a[100:103]", b1); \
        MF(acc0, "a[8:11]",  b2); MF(acc1, "a[24:27]", b2); \
        MF(acc2, "a[40:43]", b2); MF(acc3, "a[56:59]", b2); \
        MF(acc4, "a[72:75]", b2); MF(acc5, "a[88:91]", b2); \
        MF(acc6, "a[104:107]", b2); \
        MF(acc0, "a[12:15]", b3); MF(acc1, "a[28:31]", b3); \
        MF(acc2, "a[44:47]", b3); MF(acc3, "a[60:63]", b3); \
        MF(acc4, "a[76:79]", b3); MF(acc5, "a[92:95]", b3); \
        MF(acc6, "a[108:111]", b3); \
        asm volatile("s_nop 7\n\ts_nop 7\n\tv_or_b32 %0, 0, %1" \
                     : "=v"(colg) : "v"(col)); \
    } else { \
        asm("" : "+v"(acc0), "+v"(acc1), "+v"(acc2), "+v"(acc3), \
                 "+v"(acc4), "+v"(acc5), "+v"(acc6)); \
        colg = col; \
    } \
    f32x4 g = (colg == 1) ? acc1 : acc0; \
    g = (colg == 2) ? acc2 : g; \
    g = (colg == 3) ? acc3 : g; \
    g = (colg == 4) ? acc4 : g; \
    g = (colg == 5) ? acc5 : g; \
    g = (colg == 6) ? acc6 : g; \
    float iv, fv, gv, ov; \
    if constexpr (MODE != 3) { \
        iv = sigmoid_fast(g[0]); fv = sigmoid_fast(g[1]); \
        gv = tanh_fast(g[2]);    ov = sigmoid_fast(g[3]); \
    } else { iv = g[0]; fv = g[1]; gv = g[2]; ov = g[3]; } \
    c = fv * c + iv * gv; \
    float h = (MODE != 3) ? (ov * tanh_fast(c)) : (ov * c); \
    if (act) { hlast = h; hbuf[cur ^ 1][u] = (_Float16)h; } \
    if constexpr (MODE != 4) { BAR(); } \
    else { asm volatile("s_waitcnt lgkmcnt(0)" ::: "memory"); } \
    cur ^= 1; \
    XP = xnew_; }

    for (int t = 0; t < T; t += 4) {
        SUBSTEP(xa, t + 4)
        SUBSTEP(xb, t + 5)
        SUBSTEP(xc, t + 6)
        SUBSTEP(xd, t + 7)
    }
#undef SUBSTEP
#undef XROW

    if (act) hfin[u] = hlast * wlin[u];
    __syncthreads();
    if (tid == 0) {
        float s = blin[0];
        for (int k = 0; k < 100; ++k) s += hfin[k];
        outp[0] = s;
    }
}

extern "C" void kernel_launch(void* const* d_in, const int* in_sizes, int n_in,
                              void* d_out, int out_size, void* d_ws, size_t ws_size,
                              hipStream_t stream) {
    const float* input = (const float*)d_in[0];  // [T][IN]
    const float* w_ih  = (const float*)d_in[1];  // [4H][IN]
    const float* w_hh  = (const float*)d_in[2];  // [4H][H]
    const float* b_ih  = (const float*)d_in[3];  // [4H]
    const float* b_hh  = (const float*)d_in[4];  // [4H]
    const float* w_lin = (const float*)d_in[5];  // [H]
    const float* b_lin = (const float*)d_in[6];  // [1]
    float* out = (float*)d_out;

    const int FH = in_sizes[3];            // 400
    const int IN = in_sizes[1] / FH;       // 3000
    const int T  = in_sizes[0] / IN;       // 8192

    float* xg = (float*)d_ws;              // [T][FH] = 13.1 MB (permuted)

    dim3 grid((T + GBM - 1) / GBM, (FH + GBN - 1) / GBN);
    gates_gemm<<<grid, 256, 0, stream>>>(input, w_ih, b_ih, b_hh, xg, T, IN, FH);

    // real result
    lstm_ablate<0><<<1, 256, 0, stream>>>(xg, w_hh, w_lin, b_lin, out, T);

    // diagnostic ablations (T/4 steps each, outputs into the xg tail —
    // rewritten by gates_gemm on every replay; real scan already consumed it)
    float* dbg = xg + (size_t)T * 400 - 8;
    lstm_ablate<1><<<1, 256, 0, stream>>>(xg, w_hh, w_lin, b_lin, dbg + 0, T / 4);
    lstm_ablate<2><<<1, 256, 0, stream>>>(xg, w_hh, w_lin, b_lin, dbg + 1, T / 4);
    lstm_ablate<3><<<1, 256, 0, stream>>>(xg, w_hh, w_lin, b_lin, dbg + 2, T / 4);
    lstm_ablate<4><<<1, 256, 0, stream>>>(xg, w_hh, w_lin, b_lin, dbg + 3, T / 4);
}

// Round 14
// 5308.210 us; speedup vs baseline: 1.7421x; 1.7421x over previous
//
#include <hip/hip_runtime.h>
#include <hip/hip_bf16.h>

// LSTM: T=8192, IN=3000, H=100 (4H=400), torch gate order i,f,g,o.
// Phase 1: xg[T][400] = input @ w_ih^T + (b_ih+b_hh), PERMUTED cols (4u+g).
// Phase 2: single-workgroup MFMA scan (R8 structure). A-frags in physical
//   AGPRs a0..a111; B = h (f16 LDS, dbuf) broadcast; D layout gives lane
//   16q+col all 4 gates of unit 4*(tb+col)+q; 1 raw barrier/step.
// ROUND-14 FIX vs R9..R13 (~1390 cyc/step, 3 nulls): every version ended
// substeps with "XP = xnew_" -- a register copy of the just-issued xg load
// IN THE SAME SUBSTEP. The backend's vmcnt wait lands before that copy ->
// effective prefetch depth 1 (~550 cyc in flight vs ~600-900 cyc latency)
// -> ~400 cyc stall/step that survived every ablation (R13: 31% base).
// Now the load goes DIRECTLY into the named register right after its old
// value is consumed; first next use is 4 substeps (~2300 cyc) later.

#define GBM 128
#define GBN 128
#define GBK 16

typedef _Float16 h2_t  __attribute__((ext_vector_type(2)));
typedef _Float16 f16x8 __attribute__((ext_vector_type(8)));
typedef float    f32x4 __attribute__((ext_vector_type(4)));

__global__ __launch_bounds__(256) void gates_gemm(
    const float* __restrict__ A,    // [T][IN]
    const float* __restrict__ W,    // [FH][IN]
    const float* __restrict__ bih,  // [FH]
    const float* __restrict__ bhh,  // [FH]
    float* __restrict__ XG,         // [T][FH]  (permuted columns)
    int T, int IN, int FH)
{
    __shared__ __align__(16) float As[GBK][GBM];
    __shared__ __align__(16) float Bs[GBK][GBN];
    const int bm = blockIdx.x * GBM;
    const int bn = blockIdx.y * GBN;
    const int tid = (int)threadIdx.x;
    const int tx = tid & 15, ty = tid >> 4;
    const int H = FH >> 2;   // 100

    float acc[8][8];
    #pragma unroll
    for (int i = 0; i < 8; ++i)
        #pragma unroll
        for (int j = 0; j < 8; ++j) acc[i][j] = 0.f;

    for (int k0 = 0; k0 < IN; k0 += GBK) {
        __syncthreads();
        #pragma unroll
        for (int q = 0; q < 2; ++q) {
            int idx = tid + q * 256;
            int row = idx >> 2;
            int kq  = (idx & 3) << 2;
            int gk  = k0 + kq;
            float4 av = make_float4(0.f, 0.f, 0.f, 0.f);
            float4 bv = make_float4(0.f, 0.f, 0.f, 0.f);
            if (gk < IN) {
                av = *(const float4*)&A[(size_t)(bm + row) * IN + gk];
                if (bn + row < FH)
                    bv = *(const float4*)&W[(size_t)(bn + row) * IN + gk];
            }
            As[kq + 0][row] = av.x; As[kq + 1][row] = av.y;
            As[kq + 2][row] = av.z; As[kq + 3][row] = av.w;
            Bs[kq + 0][row] = bv.x; Bs[kq + 1][row] = bv.y;
            Bs[kq + 2][row] = bv.z; Bs[kq + 3][row] = bv.w;
        }
        __syncthreads();
        #pragma unroll
        for (int kk = 0; kk < GBK; ++kk) {
            float4 a0 = *(const float4*)&As[kk][ty * 4];
            float4 a1 = *(const float4*)&As[kk][64 + ty * 4];
            float4 b0 = *(const float4*)&Bs[kk][tx * 4];
            float4 b1 = *(const float4*)&Bs[kk][64 + tx * 4];
            float am[8] = {a0.x, a0.y, a0.z, a0.w, a1.x, a1.y, a1.z, a1.w};
            float bn_[8] = {b0.x, b0.y, b0.z, b0.w, b1.x, b1.y, b1.z, b1.w};
            #pragma unroll
            for (int i = 0; i < 8; ++i)
                #pragma unroll
                for (int j = 0; j < 8; ++j)
                    acc[i][j] = fmaf(am[i], bn_[j], acc[i][j]);
        }
    }

    #pragma unroll
    for (int i = 0; i < 8; ++i) {
        int r = bm + ((i < 4) ? (ty * 4 + i) : (64 + ty * 4 + (i - 4)));
        #pragma unroll
        for (int j = 0; j < 8; ++j) {
            int cidx = bn + ((j < 4) ? (tx * 4 + j) : (64 + tx * 4 + (j - 4)));
            if (cidx < FH) {
                int pc = 4 * (cidx % H) + cidx / H;   // unit-major permutation
                XG[(size_t)r * FH + pc] = acc[i][j] + bih[cidx] + bhh[cidx];
            }
        }
    }
}

__device__ __forceinline__ float sigmoid_fast(float x) {
    return 1.f / (1.f + __expf(-x));
}
__device__ __forceinline__ float tanh_fast(float x) {
    return 1.f - 2.f / (__expf(2.f * x) + 1.f);
}

// pack W[k], W[k+1] (f32) into one dword of two f16 (zero past K=100)
__device__ __forceinline__ float pack_pair(const float* rp, int k) {
    float a = 0.f, b = 0.f;
    if (k < 100) { a = rp[k]; b = rp[k + 1]; }
    h2_t p = {(_Float16)a, (_Float16)b};
    return __builtin_bit_cast(float, p);
}

#define ACLOB \
    "a0","a1","a2","a3","a4","a5","a6","a7","a8","a9","a10","a11","a12","a13",\
    "a14","a15","a16","a17","a18","a19","a20","a21","a22","a23","a24","a25",\
    "a26","a27","a28","a29","a30","a31","a32","a33","a34","a35","a36","a37",\
    "a38","a39","a40","a41","a42","a43","a44","a45","a46","a47","a48","a49",\
    "a50","a51","a52","a53","a54","a55","a56","a57","a58","a59","a60","a61",\
    "a62","a63","a64","a65","a66","a67","a68","a69","a70","a71","a72","a73",\
    "a74","a75","a76","a77","a78","a79","a80","a81","a82","a83","a84","a85",\
    "a86","a87","a88","a89","a90","a91","a92","a93","a94","a95","a96","a97",\
    "a98","a99","a100","a101","a102","a103","a104","a105","a106","a107",\
    "a108","a109","a110","a111"

#define WRW(N, V) \
    asm volatile("v_accvgpr_write_b32 a" #N ", %0" :: "v"(V) : "a" #N)

#define LF(m, ks, N0, N1, N2, N3) { \
    const int kb_ = 32 * (ks) + 8 * q; \
    WRW(N0, pack_pair(rowp[m], kb_ + 0)); \
    WRW(N1, pack_pair(rowp[m], kb_ + 2)); \
    WRW(N2, pack_pair(rowp[m], kb_ + 4)); \
    WRW(N3, pack_pair(rowp[m], kb_ + 6)); }

#define MF(ACC, AR, B) \
    asm volatile("v_mfma_f32_16x16x32_f16 %0, " AR ", %1, %0" \
                 : "+v"(ACC) : "v"(B) : ACLOB)

// raw barrier: orders LDS (lgkmcnt) but leaves global loads in flight
#define BAR() asm volatile("s_waitcnt lgkmcnt(0)\n\ts_barrier" ::: "memory")

__global__ __launch_bounds__(256, 1) void lstm_scan_pf4(
    const float* __restrict__ XGp,   // [T][400] permuted (4u+g)
    const float* __restrict__ Whh,   // [400][100] original layout
    const float* __restrict__ wlin,  // [100]
    const float* __restrict__ blin,  // [1]
    float* __restrict__ out, int T)
{
    __shared__ __align__(16) _Float16 hbuf[2][128];
    __shared__ float hfin[100];
    const int tid = (int)threadIdx.x;
    const int w   = tid >> 6;
    const int l   = tid & 63;
    const int q   = l >> 4;
    const int col = l & 15;
    const int NT  = (w == 0) ? 7 : 6;
    const int tb  = (w == 0) ? 0 : 7 + 6 * (w - 1);

    const float* rowp[7];
    #pragma unroll
    for (int m = 0; m < 7; ++m) {
        int mg = tb + m; if (mg > 24) mg = 24;
        int R  = 16 * mg + col;
        rowp[m] = Whh + (size_t)((R >> 2) + 100 * (R & 3)) * 100;
    }

    LF(0,0,  0,  1,  2,  3)  LF(0,1,  4,  5,  6,  7)
    LF(0,2,  8,  9, 10, 11)  LF(0,3, 12, 13, 14, 15)
    LF(1,0, 16, 17, 18, 19)  LF(1,1, 20, 21, 22, 23)
    LF(1,2, 24, 25, 26, 27)  LF(1,3, 28, 29, 30, 31)
    LF(2,0, 32, 33, 34, 35)  LF(2,1, 36, 37, 38, 39)
    LF(2,2, 40, 41, 42, 43)  LF(2,3, 44, 45, 46, 47)
    LF(3,0, 48, 49, 50, 51)  LF(3,1, 52, 53, 54, 55)
    LF(3,2, 56, 57, 58, 59)  LF(3,3, 60, 61, 62, 63)
    LF(4,0, 64, 65, 66, 67)  LF(4,1, 68, 69, 70, 71)
    LF(4,2, 72, 73, 74, 75)  LF(4,3, 76, 77, 78, 79)
    LF(5,0, 80, 81, 82, 83)  LF(5,1, 84, 85, 86, 87)
    LF(5,2, 88, 89, 90, 91)  LF(5,3, 92, 93, 94, 95)
    LF(6,0, 96, 97, 98, 99)  LF(6,1,100,101,102,103)
    LF(6,2,104,105,106,107)  LF(6,3,108,109,110,111)

    if (tid < 128) {
        hbuf[0][tid] = (_Float16)0.f;
        hbuf[1][tid] = (_Float16)0.f;
    }

    const bool act = (col < NT);
    const int  u   = act ? (4 * (tb + col) + q) : 0;

    float c = 0.f, hlast = 0.f;
    int cur = 0;

#define XROW(i) (*(const f32x4*)(XGp + (size_t)((i) < T ? (i) : (T - 1)) * 400 + 4 * u))
    // depth-4 prefetch: 4 named registers, loads go DIRECTLY into them
    f32x4 xa = XROW(0), xb = XROW(1), xc = XROW(2), xd = XROW(3);
    BAR();

#define SUBSTEP(XP, TNEXT) { \
    const _Float16* hb = hbuf[cur]; \
    f16x8 b0 = *(const f16x8*)(hb +       8 * q); \
    f16x8 b1 = *(const f16x8*)(hb +  32 + 8 * q); \
    f16x8 b2 = *(const f16x8*)(hb +  64 + 8 * q); \
    f16x8 b3 = *(const f16x8*)(hb +  96 + 8 * q); \
    f32x4 acc0 = XP, acc1 = XP, acc2 = XP, acc3 = XP; \
    f32x4 acc4 = XP, acc5 = XP, acc6 = XP; \
    XP = XROW(TNEXT);   /* direct load into named reg; next use 4 steps away */ \
    asm volatile("s_nop 1" ::: ); \
    MF(acc0, "a[0:3]",   b0); MF(acc1, "a[16:19]", b0); \
    MF(acc2, "a[32:35]", b0); MF(acc3, "a[48:51]", b0); \
    MF(acc4, "a[64:67]", b0); MF(acc5, "a[80:83]", b0); \
    MF(acc6, "a[96:99]", b0); \
    MF(acc0, "a[4:7]",   b1); MF(acc1, "a[20:23]", b1); \
    MF(acc2, "a[36:39]", b1); MF(acc3, "a[52:55]", b1); \
    MF(acc4, "a[68:71]", b1); MF(acc5, "a[84:87]", b1); \
    MF(acc6, "a[100:103]", b1); \
    MF(acc0, "a[8:11]",  b2); MF(acc1, "a[24:27]", b2); \
    MF(acc2, "a[40:43]", b2); MF(acc3, "a[56:59]", b2); \
    MF(acc4, "a[72:75]", b2); MF(acc5, "a[88:91]", b2); \
    MF(acc6, "a[104:107]", b2); \
    MF(acc0, "a[12:15]", b3); MF(acc1, "a[28:31]", b3); \
    MF(acc2, "a[44:47]", b3); MF(acc3, "a[60:63]", b3); \
    MF(acc4, "a[76:79]", b3); MF(acc5, "a[92:95]", b3); \
    MF(acc6, "a[108:111]", b3); \
    int colg; \
    asm volatile("s_nop 7\n\ts_nop 7\n\tv_or_b32 %0, 0, %1" \
                 : "=v"(colg) : "v"(col)); \
    f32x4 g = (colg == 1) ? acc1 : acc0; \
    g = (colg == 2) ? acc2 : g; \
    g = (colg == 3) ? acc3 : g; \
    g = (colg == 4) ? acc4 : g; \
    g = (colg == 5) ? acc5 : g; \
    g = (colg == 6) ? acc6 : g; \
    float iv = sigmoid_fast(g[0]); \
    float fv = sigmoid_fast(g[1]); \
    float gv = tanh_fast   (g[2]); \
    float ov = sigmoid_fast(g[3]); \
    c = fv * c + iv * gv; \
    float h = ov * tanh_fast(c); \
    if (act) { hlast = h; hbuf[cur ^ 1][u] = (_Float16)h; } \
    BAR(); \
    cur ^= 1; }

    for (int t = 0; t < T; t += 4) {
        SUBSTEP(xa, t + 4)
        SUBSTEP(xb, t + 5)
        SUBSTEP(xc, t + 6)
        SUBSTEP(xd, t + 7)
    }
#undef SUBSTEP
#undef XROW

    if (act) hfin[u] = hlast * wlin[u];
    __syncthreads();
    if (tid == 0) {
        float s = blin[0];
        for (int k = 0; k < 100; ++k) s += hfin[k];
        out[0] = s;
    }
}

extern "C" void kernel_launch(void* const* d_in, const int* in_sizes, int n_in,
                              void* d_out, int out_size, void* d_ws, size_t ws_size,
                              hipStream_t stream) {
    const float* input = (const float*)d_in[0];  // [T][IN]
    const float* w_ih  = (const float*)d_in[1];  // [4H][IN]
    const float* w_hh  = (const float*)d_in[2];  // [4H][H]
    const float* b_ih  = (const float*)d_in[3];  // [4H]
    const float* b_hh  = (const float*)d_in[4];  // [4H]
    const float* w_lin = (const float*)d_in[5];  // [H]
    const float* b_lin = (const float*)d_in[6];  // [1]
    float* out = (float*)d_out;

    const int FH = in_sizes[3];            // 400
    const int IN = in_sizes[1] / FH;       // 3000
    const int T  = in_sizes[0] / IN;       // 8192

    float* xg = (float*)d_ws;              // [T][FH] = 13.1 MB (permuted)

    dim3 grid((T + GBM - 1) / GBM, (FH + GBN - 1) / GBN);
    gates_gemm<<<grid, 256, 0, stream>>>(input, w_ih, b_ih, b_hh, xg, T, IN, FH);
    lstm_scan_pf4<<<1, 256, 0, stream>>>(xg, w_hh, w_lin, b_lin, out, T);
}

// Round 16
// 4164.910 us; speedup vs baseline: 2.2203x; 1.2745x over previous
//
#include <hip/hip_runtime.h>
#include <hip/hip_bf16.h>

// LSTM: T=8192, IN=3000, H=100 (4H=400), torch gate order i,f,g,o.
// Phase 1: xg[T][400] = input @ w_ih^T + (b_ih+b_hh), PERMUTED cols (4u+g).
// Phase 2: single-workgroup scan, 256 threads / 4 waves, VALU dot2 engine,
//          weights pinned in PHYSICAL VGPRs v152..v255.
// ROUND-16: R15 proved v_dot2 cannot read AGPRs (assembler error). The only
// zero-overhead weight store VALU can reach is the VGPR file itself, and the
// compiler refuses to keep 104 values live (R1-R6). So: weights are mov'd
// ONCE into v152..v255, and the whole matvec is ONE asm block per step:
//   v96..v147  = 13x ds_read_b128 of h (f16, LDS double buffer)
//   v148..v151 = 4 interleaved dot2 accumulator chains (8-cyc reuse)
//   counted lgkmcnt(9/5/1/0) waits so dot2 issue overlaps LDS latency
// All of v96-v255 is clobbered by the block -> no compiler value can live
// there across it; compiler's ~90-value working set allocates low (v0-95).
// Scaffolding = R12-verified: lane-pair unit layout (even lane: gates i,f;
// odd: g,o), divergence-free unified nonlinearity, ONE ds_swizzle exchange,
// lgkmcnt-only barrier, depth-4 direct-load xg prefetch.

#define GBM 128
#define GBN 128
#define GBK 16

typedef _Float16 h2_t __attribute__((ext_vector_type(2)));

__global__ __launch_bounds__(256) void gates_gemm(
    const float* __restrict__ A,    // [T][IN]
    const float* __restrict__ W,    // [FH][IN]
    const float* __restrict__ bih,  // [FH]
    const float* __restrict__ bhh,  // [FH]
    float* __restrict__ XG,         // [T][FH]  (permuted columns)
    int T, int IN, int FH)
{
    __shared__ __align__(16) float As[GBK][GBM];
    __shared__ __align__(16) float Bs[GBK][GBN];
    const int bm = blockIdx.x * GBM;
    const int bn = blockIdx.y * GBN;
    const int tid = (int)threadIdx.x;
    const int tx = tid & 15, ty = tid >> 4;
    const int H = FH >> 2;   // 100

    float acc[8][8];
    #pragma unroll
    for (int i = 0; i < 8; ++i)
        #pragma unroll
        for (int j = 0; j < 8; ++j) acc[i][j] = 0.f;

    for (int k0 = 0; k0 < IN; k0 += GBK) {
        __syncthreads();
        #pragma unroll
        for (int q = 0; q < 2; ++q) {
            int idx = tid + q * 256;
            int row = idx >> 2;
            int kq  = (idx & 3) << 2;
            int gk  = k0 + kq;
            float4 av = make_float4(0.f, 0.f, 0.f, 0.f);
            float4 bv = make_float4(0.f, 0.f, 0.f, 0.f);
            if (gk < IN) {
                av = *(const float4*)&A[(size_t)(bm + row) * IN + gk];
                if (bn + row < FH)
                    bv = *(const float4*)&W[(size_t)(bn + row) * IN + gk];
            }
            As[kq + 0][row] = av.x; As[kq + 1][row] = av.y;
            As[kq + 2][row] = av.z; As[kq + 3][row] = av.w;
            Bs[kq + 0][row] = bv.x; Bs[kq + 1][row] = bv.y;
            Bs[kq + 2][row] = bv.z; Bs[kq + 3][row] = bv.w;
        }
        __syncthreads();
        #pragma unroll
        for (int kk = 0; kk < GBK; ++kk) {
            float4 a0 = *(const float4*)&As[kk][ty * 4];
            float4 a1 = *(const float4*)&As[kk][64 + ty * 4];
            float4 b0 = *(const float4*)&Bs[kk][tx * 4];
            float4 b1 = *(const float4*)&Bs[kk][64 + tx * 4];
            float am[8] = {a0.x, a0.y, a0.z, a0.w, a1.x, a1.y, a1.z, a1.w};
            float bn_[8] = {b0.x, b0.y, b0.z, b0.w, b1.x, b1.y, b1.z, b1.w};
            #pragma unroll
            for (int i = 0; i < 8; ++i)
                #pragma unroll
                for (int j = 0; j < 8; ++j)
                    acc[i][j] = fmaf(am[i], bn_[j], acc[i][j]);
        }
    }

    #pragma unroll
    for (int i = 0; i < 8; ++i) {
        int r = bm + ((i < 4) ? (ty * 4 + i) : (64 + ty * 4 + (i - 4)));
        #pragma unroll
        for (int j = 0; j < 8; ++j) {
            int cidx = bn + ((j < 4) ? (tx * 4 + j) : (64 + tx * 4 + (j - 4)));
            if (cidx < FH) {
                int pc = 4 * (cidx % H) + cidx / H;   // unit-major permutation
                XG[(size_t)r * FH + pc] = acc[i][j] + bih[cidx] + bhh[cidx];
            }
        }
    }
}

// pack W[k], W[k+1] (f32) into one dword of two f16 (zero past K=100)
__device__ __forceinline__ float pack_pair(const float* rp, int k) {
    float a = 0.f, b = 0.f;
    if (k < 100) { a = rp[k]; b = rp[k + 1]; }
    h2_t p = {(_Float16)a, (_Float16)b};
    return __builtin_bit_cast(float, p);
}

// write one weight dword into a PHYSICAL VGPR (once, at startup)
#define INITW(R, V) \
    asm volatile("v_mov_b32 v" #R ", %0" :: "v"(V) : "v" #R)

// one dot2 line inside the big block: vA += vW . vH  (all physical)
#define DD(A, W, Hr) "v_dot2_f32_f16 v" #A ", v" #W ", v" #Hr ", v" #A "\n\t"

// clobbers: everything the big block owns (v96..v255)
#define VCLOB \
  "v96","v97","v98","v99","v100","v101","v102","v103","v104","v105","v106",\
  "v107","v108","v109","v110","v111","v112","v113","v114","v115","v116",\
  "v117","v118","v119","v120","v121","v122","v123","v124","v125","v126",\
  "v127","v128","v129","v130","v131","v132","v133","v134","v135","v136",\
  "v137","v138","v139","v140","v141","v142","v143","v144","v145","v146",\
  "v147","v148","v149","v150","v151","v152","v153","v154","v155","v156",\
  "v157","v158","v159","v160","v161","v162","v163","v164","v165","v166",\
  "v167","v168","v169","v170","v171","v172","v173","v174","v175","v176",\
  "v177","v178","v179","v180","v181","v182","v183","v184","v185","v186",\
  "v187","v188","v189","v190","v191","v192","v193","v194","v195","v196",\
  "v197","v198","v199","v200","v201","v202","v203","v204","v205","v206",\
  "v207","v208","v209","v210","v211","v212","v213","v214","v215","v216",\
  "v217","v218","v219","v220","v221","v222","v223","v224","v225","v226",\
  "v227","v228","v229","v230","v231","v232","v233","v234","v235","v236",\
  "v237","v238","v239","v240","v241","v242","v243","v244","v245","v246",\
  "v247","v248","v249","v250","v251","v252","v253","v254","v255"

// raw barrier: orders LDS, leaves global loads in flight
#define BAR() asm volatile("s_waitcnt lgkmcnt(0)\n\ts_barrier" ::: "memory")

__global__ __launch_bounds__(256, 1) void lstm_scan_pinv(
    const float* __restrict__ XGp,   // [T][400] permuted (4u+g)
    const float* __restrict__ Whh,   // [400][100] original layout
    const float* __restrict__ wlin,  // [100]
    const float* __restrict__ blin,  // [1]
    float* __restrict__ out, int T)
{
    __shared__ __align__(16) _Float16 hbuf[2][104];  // 208 B per buffer
    __shared__ float hfin[100];
    const int tid    = (int)threadIdx.x;
    const int parity = tid & 1;          // 0: gates i,f   1: gates g,o
    const int p      = tid >> 1;         // unit index
    const int pc     = (p < 100) ? p : 99;
    const bool act   = (parity == 0) && (p < 100);
    const float kk   = 1.f + (float)parity;   // 1 -> sigmoid, 2 -> tanh

    // gate rows: even = (u, u+100) = (i,f); odd = (u+200, u+300) = (g,o)
    const float* r0p = Whh + (size_t)(pc + parity * 200) * 100;
    const float* r1p = Whh + (size_t)(pc + 100 + parity * 200) * 100;

    // ---- weights into PHYSICAL VGPRs: row0 -> v152+j, row1 -> v204+j ----
#define LW(j, R0, R1) { INITW(R0, pack_pair(r0p, 2*(j))); \
                        INITW(R1, pack_pair(r1p, 2*(j))); }
    LW(0,152,204)  LW(1,153,205)  LW(2,154,206)  LW(3,155,207)
    LW(4,156,208)  LW(5,157,209)  LW(6,158,210)  LW(7,159,211)
    LW(8,160,212)  LW(9,161,213)  LW(10,162,214) LW(11,163,215)
    LW(12,164,216) LW(13,165,217) LW(14,166,218) LW(15,167,219)
    LW(16,168,220) LW(17,169,221) LW(18,170,222) LW(19,171,223)
    LW(20,172,224) LW(21,173,225) LW(22,174,226) LW(23,175,227)
    LW(24,176,228) LW(25,177,229) LW(26,178,230) LW(27,179,231)
    LW(28,180,232) LW(29,181,233) LW(30,182,234) LW(31,183,235)
    LW(32,184,236) LW(33,185,237) LW(34,186,238) LW(35,187,239)
    LW(36,188,240) LW(37,189,241) LW(38,190,242) LW(39,191,243)
    LW(40,192,244) LW(41,193,245) LW(42,194,246) LW(43,195,247)
    LW(44,196,248) LW(45,197,249) LW(46,198,250) LW(47,199,251)
    LW(48,200,252) LW(49,201,253) LW(50,202,254) LW(51,203,255)
#undef LW

    if (tid < 104) { hbuf[0][tid] = (_Float16)0.f; hbuf[1][tid] = (_Float16)0.f; }

    const unsigned hb_base = (unsigned)(uintptr_t)&hbuf[0][0];

    // xg: even lane reads permuted cols (4u,4u+1)=(i,f); odd (4u+2,4u+3)=(g,o)
    const int xoff = 4 * pc + 2 * parity;
#define XR(i) (*(const float2*)(XGp + (size_t)((i) < T ? (i) : (T - 1)) * 400 + xoff))

    float2 xa = XR(0), xb = XR(1), xc = XR(2), xd = XR(3);

    float c = 0.f, hlast = 0.f;
    int cur = 0;
    BAR();

    // ---- the whole matvec: one asm block (h loads + 104 dot2) ----
#define MATVEC(G0, G1, HB, X0, X1) \
    asm volatile( \
        "v_mov_b32 v148, %[x0]\n\t" \
        "v_mov_b32 v149, %[x1]\n\t" \
        "v_mov_b32 v150, 0\n\t" \
        "v_mov_b32 v151, 0\n\t" \
        "ds_read_b128 v[96:99], %[hb]\n\t" \
        "ds_read_b128 v[100:103], %[hb] offset:16\n\t" \
        "ds_read_b128 v[104:107], %[hb] offset:32\n\t" \
        "ds_read_b128 v[108:111], %[hb] offset:48\n\t" \
        "ds_read_b128 v[112:115], %[hb] offset:64\n\t" \
        "ds_read_b128 v[116:119], %[hb] offset:80\n\t" \
        "ds_read_b128 v[120:123], %[hb] offset:96\n\t" \
        "ds_read_b128 v[124:127], %[hb] offset:112\n\t" \
        "ds_read_b128 v[128:131], %[hb] offset:128\n\t" \
        "ds_read_b128 v[132:135], %[hb] offset:144\n\t" \
        "ds_read_b128 v[136:139], %[hb] offset:160\n\t" \
        "ds_read_b128 v[140:143], %[hb] offset:176\n\t" \
        "ds_read_b128 v[144:147], %[hb] offset:192\n\t" \
        "s_waitcnt lgkmcnt(9)\n\t" \
        DD(148,152,96)  DD(149,204,96)  DD(150,153,97)  DD(151,205,97) \
        DD(148,154,98)  DD(149,206,98)  DD(150,155,99)  DD(151,207,99) \
        DD(148,156,100) DD(149,208,100) DD(150,157,101) DD(151,209,101) \
        DD(148,158,102) DD(149,210,102) DD(150,159,103) DD(151,211,103) \
        DD(148,160,104) DD(149,212,104) DD(150,161,105) DD(151,213,105) \
        DD(148,162,106) DD(149,214,106) DD(150,163,107) DD(151,215,107) \
        DD(148,164,108) DD(149,216,108) DD(150,165,109) DD(151,217,109) \
        DD(148,166,110) DD(149,218,110) DD(150,167,111) DD(151,219,111) \
        "s_waitcnt lgkmcnt(5)\n\t" \
        DD(148,168,112) DD(149,220,112) DD(150,169,113) DD(151,221,113) \
        DD(148,170,114) DD(149,222,114) DD(150,171,115) DD(151,223,115) \
        DD(148,172,116) DD(149,224,116) DD(150,173,117) DD(151,225,117) \
        DD(148,174,118) DD(149,226,118) DD(150,175,119) DD(151,227,119) \
        DD(148,176,120) DD(149,228,120) DD(150,177,121) DD(151,229,121) \
        DD(148,178,122) DD(149,230,122) DD(150,179,123) DD(151,231,123) \
        DD(148,180,124) DD(149,232,124) DD(150,181,125) DD(151,233,125) \
        DD(148,182,126) DD(149,234,126) DD(150,183,127) DD(151,235,127) \
        "s_waitcnt lgkmcnt(1)\n\t" \
        DD(148,184,128) DD(149,236,128) DD(150,185,129) DD(151,237,129) \
        DD(148,186,130) DD(149,238,130) DD(150,187,131) DD(151,239,131) \
        DD(148,188,132) DD(149,240,132) DD(150,189,133) DD(151,241,133) \
        DD(148,190,134) DD(149,242,134) DD(150,191,135) DD(151,243,135) \
        DD(148,192,136) DD(149,244,136) DD(150,193,137) DD(151,245,137) \
        DD(148,194,138) DD(149,246,138) DD(150,195,139) DD(151,247,139) \
        DD(148,196,140) DD(149,248,140) DD(150,197,141) DD(151,249,141) \
        DD(148,198,142) DD(149,250,142) DD(150,199,143) DD(151,251,143) \
        "s_waitcnt lgkmcnt(0)\n\t" \
        DD(148,200,144) DD(149,252,144) DD(150,201,145) DD(151,253,145) \
        DD(148,202,146) DD(149,254,146) DD(150,203,147) DD(151,255,147) \
        "v_add_f32 %[g0], v148, v150\n\t" \
        "v_add_f32 %[g1], v149, v151" \
        : [g0]"=v"(G0), [g1]"=v"(G1) \
        : [hb]"v"(HB), [x0]"v"(X0), [x1]"v"(X1) \
        : VCLOB, "memory")

#define SUBSTEP(XP, TNEXT) { \
    unsigned hb_ = hb_base + (unsigned)(cur * 208); \
    float g0, g1; \
    MATVEC(g0, g1, hb_, XP.x, XP.y); \
    XP = XR(TNEXT);   /* direct load into named reg; next use 4 steps away */ \
    /* unified nonlinearity: even->sigmoid(g0)=iv, odd->tanh(g0)=gv */ \
    float e0  = __expf(kk * g0); \
    float t0v = 1.f - kk * __builtin_amdgcn_rcpf(e0 + 1.f); \
    float e1  = __expf(-g1); \
    float t1v = __builtin_amdgcn_rcpf(1.f + e1);   /* s(f) / s(o) */ \
    float rg_, ro_; \
    asm volatile("ds_swizzle_b32 %0, %2 offset:0x041F\n\t" \
                 "ds_swizzle_b32 %1, %3 offset:0x041F\n\t" \
                 "s_waitcnt lgkmcnt(0)" \
                 : "=&v"(rg_), "=&v"(ro_) : "v"(t0v), "v"(t1v)); \
    c = fmaf(t1v, c, t0v * rg_);          /* fv*c + iv*gv (even lanes) */ \
    float e2 = __expf(2.f * c); \
    float th = 1.f - 2.f * __builtin_amdgcn_rcpf(e2 + 1.f); \
    float hv_ = ro_ * th;                 /* ov * tanh(c) */ \
    if (act) { hlast = hv_; hbuf[cur ^ 1][p] = (_Float16)hv_; } \
    BAR(); \
    cur ^= 1; }

    for (int t = 0; t < T; t += 4) {
        SUBSTEP(xa, t + 4)
        SUBSTEP(xb, t + 5)
        SUBSTEP(xc, t + 6)
        SUBSTEP(xd, t + 7)
    }
#undef SUBSTEP
#undef XR

    if (act) hfin[p] = hlast * wlin[p];
    __syncthreads();
    if (tid == 0) {
        float s = blin[0];
        for (int k = 0; k < 100; ++k) s += hfin[k];
        out[0] = s;
    }
}

extern "C" void kernel_launch(void* const* d_in, const int* in_sizes, int n_in,
                              void* d_out, int out_size, void* d_ws, size_t ws_size,
                              hipStream_t stream) {
    const float* input = (const float*)d_in[0];  // [T][IN]
    const float* w_ih  = (const float*)d_in[1];  // [4H][IN]
    const float* w_hh  = (const float*)d_in[2];  // [4H][H]
    const float* b_ih  = (const float*)d_in[3];  // [4H]
    const float* b_hh  = (const float*)d_in[4];  // [4H]
    const float* w_lin = (const float*)d_in[5];  // [H]
    const float* b_lin = (const float*)d_in[6];  // [1]
    float* out = (float*)d_out;

    const int FH = in_sizes[3];            // 400
    const int IN = in_sizes[1] / FH;       // 3000
    const int T  = in_sizes[0] / IN;       // 8192

    float* xg = (float*)d_ws;              // [T][FH] = 13.1 MB (permuted)

    dim3 grid((T + GBM - 1) / GBM, (FH + GBN - 1) / GBN);
    gates_gemm<<<grid, 256, 0, stream>>>(input, w_ih, b_ih, b_hh, xg, T, IN, FH);
    lstm_scan_pinv<<<1, 256, 0, stream>>>(xg, w_hh, w_lin, b_lin, out, T);
}

// Round 20
// 4163.584 us; speedup vs baseline: 2.2210x; 1.0003x over previous
//
#include <hip/hip_runtime.h>
#include <hip/hip_bf16.h>

// LSTM: T=8192, IN=3000, H=100 (4H=400), torch gate order i,f,g,o.
// Phase 1: xg[T][400] = input @ w_ih^T + (b_ih+b_hh), PERMUTED cols (4u+g).
// Phase 2: single-workgroup scan, 256 threads / 4 waves, VALU dot2 engine,
//          weights pinned in PHYSICAL VGPRs v152..v255.
// ROUND-20: VERBATIM RESTORE of the Round-16 PASSING kernel (3663 us scan,
// 4165 us total). R17/R18/R19 all failed with the identical absmax 6.836e-3;
// the only remaining deltas vs this kernel ({pad-trim, folded-C-operand})
// are analytically bit-exact identities, yet the measurements say otherwise
// -- three theories in a row contradicted. Per rigor discipline: restore the
// proven-good artifact byte-for-byte and bank it rather than risk a fourth
// speculative variant.
//   v96..v147  = 13x ds_read_b128 of h (f16, LDS double buffer)
//   v148..v151 = 4 interleaved dot2 accumulator chains (8-cyc reuse)
//   counted lgkmcnt(9/5/1/0) waits so dot2 issue overlaps LDS latency
// All of v96-v255 is clobbered by the block -> no compiler value can live
// there across it; compiler's ~90-value working set allocates low (v0-95).
// Scaffolding: lane-pair unit layout (even lane: gates i,f; odd: g,o),
// divergence-free unified nonlinearity, ONE ds_swizzle exchange,
// lgkmcnt-only barrier, depth-4 direct-load xg prefetch.

#define GBM 128
#define GBN 128
#define GBK 16

typedef _Float16 h2_t __attribute__((ext_vector_type(2)));

__global__ __launch_bounds__(256) void gates_gemm(
    const float* __restrict__ A,    // [T][IN]
    const float* __restrict__ W,    // [FH][IN]
    const float* __restrict__ bih,  // [FH]
    const float* __restrict__ bhh,  // [FH]
    float* __restrict__ XG,         // [T][FH]  (permuted columns)
    int T, int IN, int FH)
{
    __shared__ __align__(16) float As[GBK][GBM];
    __shared__ __align__(16) float Bs[GBK][GBN];
    const int bm = blockIdx.x * GBM;
    const int bn = blockIdx.y * GBN;
    const int tid = (int)threadIdx.x;
    const int tx = tid & 15, ty = tid >> 4;
    const int H = FH >> 2;   // 100

    float acc[8][8];
    #pragma unroll
    for (int i = 0; i < 8; ++i)
        #pragma unroll
        for (int j = 0; j < 8; ++j) acc[i][j] = 0.f;

    for (int k0 = 0; k0 < IN; k0 += GBK) {
        __syncthreads();
        #pragma unroll
        for (int q = 0; q < 2; ++q) {
            int idx = tid + q * 256;
            int row = idx >> 2;
            int kq  = (idx & 3) << 2;
            int gk  = k0 + kq;
            float4 av = make_float4(0.f, 0.f, 0.f, 0.f);
            float4 bv = make_float4(0.f, 0.f, 0.f, 0.f);
            if (gk < IN) {
                av = *(const float4*)&A[(size_t)(bm + row) * IN + gk];
                if (bn + row < FH)
                    bv = *(const float4*)&W[(size_t)(bn + row) * IN + gk];
            }
            As[kq + 0][row] = av.x; As[kq + 1][row] = av.y;
            As[kq + 2][row] = av.z; As[kq + 3][row] = av.w;
            Bs[kq + 0][row] = bv.x; Bs[kq + 1][row] = bv.y;
            Bs[kq + 2][row] = bv.z; Bs[kq + 3][row] = bv.w;
        }
        __syncthreads();
        #pragma unroll
        for (int kk = 0; kk < GBK; ++kk) {
            float4 a0 = *(const float4*)&As[kk][ty * 4];
            float4 a1 = *(const float4*)&As[kk][64 + ty * 4];
            float4 b0 = *(const float4*)&Bs[kk][tx * 4];
            float4 b1 = *(const float4*)&Bs[kk][64 + tx * 4];
            float am[8] = {a0.x, a0.y, a0.z, a0.w, a1.x, a1.y, a1.z, a1.w};
            float bn_[8] = {b0.x, b0.y, b0.z, b0.w, b1.x, b1.y, b1.z, b1.w};
            #pragma unroll
            for (int i = 0; i < 8; ++i)
                #pragma unroll
                for (int j = 0; j < 8; ++j)
                    acc[i][j] = fmaf(am[i], bn_[j], acc[i][j]);
        }
    }

    #pragma unroll
    for (int i = 0; i < 8; ++i) {
        int r = bm + ((i < 4) ? (ty * 4 + i) : (64 + ty * 4 + (i - 4)));
        #pragma unroll
        for (int j = 0; j < 8; ++j) {
            int cidx = bn + ((j < 4) ? (tx * 4 + j) : (64 + tx * 4 + (j - 4)));
            if (cidx < FH) {
                int pc = 4 * (cidx % H) + cidx / H;   // unit-major permutation
                XG[(size_t)r * FH + pc] = acc[i][j] + bih[cidx] + bhh[cidx];
            }
        }
    }
}

// pack W[k], W[k+1] (f32) into one dword of two f16 (zero past K=100)
__device__ __forceinline__ float pack_pair(const float* rp, int k) {
    float a = 0.f, b = 0.f;
    if (k < 100) { a = rp[k]; b = rp[k + 1]; }
    h2_t p = {(_Float16)a, (_Float16)b};
    return __builtin_bit_cast(float, p);
}

// write one weight dword into a PHYSICAL VGPR (once, at startup)
#define INITW(R, V) \
    asm volatile("v_mov_b32 v" #R ", %0" :: "v"(V) : "v" #R)

// one dot2 line: vA += vW . vH  (all physical registers)
#define DD(A, W, Hr) "v_dot2_f32_f16 v" #A ", v" #W ", v" #Hr ", v" #A "\n\t"

// clobbers: everything the big block owns (v96..v255)
#define VCLOB \
  "v96","v97","v98","v99","v100","v101","v102","v103","v104","v105","v106",\
  "v107","v108","v109","v110","v111","v112","v113","v114","v115","v116",\
  "v117","v118","v119","v120","v121","v122","v123","v124","v125","v126",\
  "v127","v128","v129","v130","v131","v132","v133","v134","v135","v136",\
  "v137","v138","v139","v140","v141","v142","v143","v144","v145","v146",\
  "v147","v148","v149","v150","v151","v152","v153","v154","v155","v156",\
  "v157","v158","v159","v160","v161","v162","v163","v164","v165","v166",\
  "v167","v168","v169","v170","v171","v172","v173","v174","v175","v176",\
  "v177","v178","v179","v180","v181","v182","v183","v184","v185","v186",\
  "v187","v188","v189","v190","v191","v192","v193","v194","v195","v196",\
  "v197","v198","v199","v200","v201","v202","v203","v204","v205","v206",\
  "v207","v208","v209","v210","v211","v212","v213","v214","v215","v216",\
  "v217","v218","v219","v220","v221","v222","v223","v224","v225","v226",\
  "v227","v228","v229","v230","v231","v232","v233","v234","v235","v236",\
  "v237","v238","v239","v240","v241","v242","v243","v244","v245","v246",\
  "v247","v248","v249","v250","v251","v252","v253","v254","v255"

// raw barrier: orders LDS, leaves global loads in flight
#define BAR() asm volatile("s_waitcnt lgkmcnt(0)\n\ts_barrier" ::: "memory")

__global__ __launch_bounds__(256, 1) void lstm_scan_pinv(
    const float* __restrict__ XGp,   // [T][400] permuted (4u+g)
    const float* __restrict__ Whh,   // [400][100] original layout
    const float* __restrict__ wlin,  // [100]
    const float* __restrict__ blin,  // [1]
    float* __restrict__ out, int T)
{
    __shared__ __align__(16) _Float16 hbuf[2][104];  // 208 B per buffer
    __shared__ float hfin[100];
    const int tid    = (int)threadIdx.x;
    const int parity = tid & 1;          // 0: gates i,f   1: gates g,o
    const int p      = tid >> 1;         // unit index
    const int pc     = (p < 100) ? p : 99;
    const bool act   = (parity == 0) && (p < 100);
    const float kk   = 1.f + (float)parity;   // 1 -> sigmoid, 2 -> tanh

    // gate rows: even = (u, u+100) = (i,f); odd = (u+200, u+300) = (g,o)
    const float* r0p = Whh + (size_t)(pc + parity * 200) * 100;
    const float* r1p = Whh + (size_t)(pc + 100 + parity * 200) * 100;

    // ---- weights into PHYSICAL VGPRs: row0 -> v152+j, row1 -> v204+j ----
#define LW(j, R0, R1) { INITW(R0, pack_pair(r0p, 2*(j))); \
                        INITW(R1, pack_pair(r1p, 2*(j))); }
    LW(0,152,204)  LW(1,153,205)  LW(2,154,206)  LW(3,155,207)
    LW(4,156,208)  LW(5,157,209)  LW(6,158,210)  LW(7,159,211)
    LW(8,160,212)  LW(9,161,213)  LW(10,162,214) LW(11,163,215)
    LW(12,164,216) LW(13,165,217) LW(14,166,218) LW(15,167,219)
    LW(16,168,220) LW(17,169,221) LW(18,170,222) LW(19,171,223)
    LW(20,172,224) LW(21,173,225) LW(22,174,226) LW(23,175,227)
    LW(24,176,228) LW(25,177,229) LW(26,178,230) LW(27,179,231)
    LW(28,180,232) LW(29,181,233) LW(30,182,234) LW(31,183,235)
    LW(32,184,236) LW(33,185,237) LW(34,186,238) LW(35,187,239)
    LW(36,188,240) LW(37,189,241) LW(38,190,242) LW(39,191,243)
    LW(40,192,244) LW(41,193,245) LW(42,194,246) LW(43,195,247)
    LW(44,196,248) LW(45,197,249) LW(46,198,250) LW(47,199,251)
    LW(48,200,252) LW(49,201,253) LW(50,202,254) LW(51,203,255)
#undef LW

    if (tid < 104) { hbuf[0][tid] = (_Float16)0.f; hbuf[1][tid] = (_Float16)0.f; }

    const unsigned hb_base = (unsigned)(uintptr_t)&hbuf[0][0];

    // xg: even lane reads permuted cols (4u,4u+1)=(i,f); odd (4u+2,4u+3)=(g,o)
    const int xoff = 4 * pc + 2 * parity;
#define XR(i) (*(const float2*)(XGp + (size_t)((i) < T ? (i) : (T - 1)) * 400 + xoff))

    float2 xa = XR(0), xb = XR(1), xc = XR(2), xd = XR(3);

    float c = 0.f, hlast = 0.f;
    int cur = 0;
    BAR();

    // ---- the whole matvec: one asm block (h loads + 104 dot2) ----
#define MATVEC(G0, G1, HB, X0, X1) \
    asm volatile( \
        "v_mov_b32 v148, %[x0]\n\t" \
        "v_mov_b32 v149, %[x1]\n\t" \
        "v_mov_b32 v150, 0\n\t" \
        "v_mov_b32 v151, 0\n\t" \
        "ds_read_b128 v[96:99], %[hb]\n\t" \
        "ds_read_b128 v[100:103], %[hb] offset:16\n\t" \
        "ds_read_b128 v[104:107], %[hb] offset:32\n\t" \
        "ds_read_b128 v[108:111], %[hb] offset:48\n\t" \
        "ds_read_b128 v[112:115], %[hb] offset:64\n\t" \
        "ds_read_b128 v[116:119], %[hb] offset:80\n\t" \
        "ds_read_b128 v[120:123], %[hb] offset:96\n\t" \
        "ds_read_b128 v[124:127], %[hb] offset:112\n\t" \
        "ds_read_b128 v[128:131], %[hb] offset:128\n\t" \
        "ds_read_b128 v[132:135], %[hb] offset:144\n\t" \
        "ds_read_b128 v[136:139], %[hb] offset:160\n\t" \
        "ds_read_b128 v[140:143], %[hb] offset:176\n\t" \
        "ds_read_b128 v[144:147], %[hb] offset:192\n\t" \
        "s_waitcnt lgkmcnt(9)\n\t" \
        DD(148,152,96)  DD(149,204,96)  DD(150,153,97)  DD(151,205,97) \
        DD(148,154,98)  DD(149,206,98)  DD(150,155,99)  DD(151,207,99) \
        DD(148,156,100) DD(149,208,100) DD(150,157,101) DD(151,209,101) \
        DD(148,158,102) DD(149,210,102) DD(150,159,103) DD(151,211,103) \
        DD(148,160,104) DD(149,212,104) DD(150,161,105) DD(151,213,105) \
        DD(148,162,106) DD(149,214,106) DD(150,163,107) DD(151,215,107) \
        DD(148,164,108) DD(149,216,108) DD(150,165,109) DD(151,217,109) \
        DD(148,166,110) DD(149,218,110) DD(150,167,111) DD(151,219,111) \
        "s_waitcnt lgkmcnt(5)\n\t" \
        DD(148,168,112) DD(149,220,112) DD(150,169,113) DD(151,221,113) \
        DD(148,170,114) DD(149,222,114) DD(150,171,115) DD(151,223,115) \
        DD(148,172,116) DD(149,224,116) DD(150,173,117) DD(151,225,117) \
        DD(148,174,118) DD(149,226,118) DD(150,175,119) DD(151,227,119) \
        DD(148,176,120) DD(149,228,120) DD(150,177,121) DD(151,229,121) \
        DD(148,178,122) DD(149,230,122) DD(150,179,123) DD(151,231,123) \
        DD(148,180,124) DD(149,232,124) DD(150,181,125) DD(151,233,125) \
        DD(148,182,126) DD(149,234,126) DD(150,183,127) DD(151,235,127) \
        "s_waitcnt lgkmcnt(1)\n\t" \
        DD(148,184,128) DD(149,236,128) DD(150,185,129) DD(151,237,129) \
        DD(148,186,130) DD(149,238,130) DD(150,187,131) DD(151,239,131) \
        DD(148,188,132) DD(149,240,132) DD(150,189,133) DD(151,241,133) \
        DD(148,190,134) DD(149,242,134) DD(150,191,135) DD(151,243,135) \
        DD(148,192,136) DD(149,244,136) DD(150,193,137) DD(151,245,137) \
        DD(148,194,138) DD(149,246,138) DD(150,195,139) DD(151,247,139) \
        DD(148,196,140) DD(149,248,140) DD(150,197,141) DD(151,249,141) \
        DD(148,198,142) DD(149,250,142) DD(150,199,143) DD(151,251,143) \
        "s_waitcnt lgkmcnt(0)\n\t" \
        DD(148,200,144) DD(149,252,144) DD(150,201,145) DD(151,253,145) \
        DD(148,202,146) DD(149,254,146) DD(150,203,147) DD(151,255,147) \
        "v_add_f32 %[g0], v148, v150\n\t" \
        "v_add_f32 %[g1], v149, v151" \
        : [g0]"=v"(G0), [g1]"=v"(G1) \
        : [hb]"v"(HB), [x0]"v"(X0), [x1]"v"(X1) \
        : VCLOB, "memory")

#define SUBSTEP(XP, TNEXT) { \
    unsigned hb_ = hb_base + (unsigned)(cur * 208); \
    float g0, g1; \
    MATVEC(g0, g1, hb_, XP.x, XP.y); \
    XP = XR(TNEXT);   /* direct load into named reg; next use 4 steps away */ \
    /* unified nonlinearity: even->sigmoid(g0)=iv, odd->tanh(g0)=gv */ \
    float e0  = __expf(kk * g0); \
    float t0v = 1.f - kk * __builtin_amdgcn_rcpf(e0 + 1.f); \
    float e1  = __expf(-g1); \
    float t1v = __builtin_amdgcn_rcpf(1.f + e1);   /* s(f) / s(o) */ \
    /* exchange with partner lane (xor 1), wait fused into same asm */ \
    float rg_, ro_; \
    asm volatile("ds_swizzle_b32 %0, %2 offset:0x041F\n\t" \
                 "ds_swizzle_b32 %1, %3 offset:0x041F\n\t" \
                 "s_waitcnt lgkmcnt(0)" \
                 : "=&v"(rg_), "=&v"(ro_) : "v"(t0v), "v"(t1v)); \
    c = fmaf(t1v, c, t0v * rg_);          /* fv*c + iv*gv (even lanes) */ \
    float e2 = __expf(2.f * c); \
    float th = 1.f - 2.f * __builtin_amdgcn_rcpf(e2 + 1.f); \
    float hv_ = ro_ * th;                 /* ov * tanh(c) */ \
    if (act) { hlast = hv_; hbuf[cur ^ 1][p] = (_Float16)hv_; } \
    BAR(); \
    cur ^= 1; }

    for (int t = 0; t < T; t += 4) {
        SUBSTEP(xa, t + 4)
        SUBSTEP(xb, t + 5)
        SUBSTEP(xc, t + 6)
        SUBSTEP(xd, t + 7)
    }
#undef SUBSTEP
#undef XR

    if (act) hfin[p] = hlast * wlin[p];
    __syncthreads();
    if (tid == 0) {
        float s = blin[0];
        for (int k = 0; k < 100; ++k) s += hfin[k];
        out[0] = s;
    }
}

extern "C" void kernel_launch(void* const* d_in, const int* in_sizes, int n_in,
                              void* d_out, int out_size, void* d_ws, size_t ws_size,
                              hipStream_t stream) {
    const float* input = (const float*)d_in[0];  // [T][IN]
    const float* w_ih  = (const float*)d_in[1];  // [4H][IN]
    const float* w_hh  = (const float*)d_in[2];  // [4H][H]
    const float* b_ih  = (const float*)d_in[3];  // [4H]
    const float* b_hh  = (const float*)d_in[4];  // [4H]
    const float* w_lin = (const float*)d_in[5];  // [H]
    const float* b_lin = (const float*)d_in[6];  // [1]
    float* out = (float*)d_out;

    const int FH = in_sizes[3];            // 400
    const int IN = in_sizes[1] / FH;       // 3000
    const int T  = in_sizes[0] / IN;       // 8192

    float* xg = (float*)d_ws;              // [T][FH] = 13.1 MB (permuted)

    dim3 grid((T + GBM - 1) / GBM, (FH + GBN - 1) / GBN);
    gates_gemm<<<grid, 256, 0, stream>>>(input, w_ih, b_ih, b_hh, xg, T, IN, FH);
    lstm_scan_pinv<<<1, 256, 0, stream>>>(xg, w_hh, w_lin, b_lin, out, T);
}